// Round 1
// baseline (254.712 us; speedup 1.0000x reference)
//
#include <hip/hip_runtime.h>
#include <math.h>

#define C_   256
#define WH   4096

// ---------------- workspace layout (floats) ----------------
// qbn   : [16][16][4096]          @ 0          (1,048,576)
// kkbn  : [16][16][4096]          @ 1,048,576  (1,048,576)
// stats : [16][16][2]             @ 2,097,152  (512)
// Wt    : [16][4096]              @ 2,097,664  (65,536)
// Mpart : [16][16 seg][32][256]   @ 2,163,200  (2,097,152)
//   (pstats [256 rows][16 chunk][2] aliases the first 8192 floats of Mpart:
//    written by proj, read by wtcomb, then overwritten by ut -> safe)
// lam   : [16][16][64]            @ 4,260,352  (16,384)

// ---- Wt (blocks 0..63) + softmax-stats combine (block 64) ----
__global__ __launch_bounds__(256) void wtcomb_kernel(const float* __restrict__ emb,
                                                     const float* __restrict__ pstats,
                                                     float* __restrict__ Wt,
                                                     float* __restrict__ stats)
{
    if (blockIdx.x == 64) {
        int row = threadIdx.x;           // 0..255 = b*16+hk
        const float* ps = pstats + (size_t)row * 32;
        float M = ps[0];
#pragma unroll
        for (int ch = 1; ch < 16; ++ch) M = fmaxf(M, ps[ch * 2]);
        float S = 0.f;
#pragma unroll
        for (int ch = 0; ch < 16; ++ch) S += ps[ch * 2 + 1] * __expf(ps[ch * 2] - M);
        stats[row * 2 + 0] = M;
        stats[row * 2 + 1] = 1.f / S;
        return;
    }
    int hk = blockIdx.x >> 2, quarter = blockIdx.x & 3;
    int h = hk >> 2, k = hk & 3;
    const float* e = emb + (size_t)(k * 4 + h) * 529;   // emb[k][h][0][0][i][j]
    __shared__ float colsum[23][64];
    for (int t = threadIdx.x; t < 23 * 64; t += 256) {
        int i = t / 64, q = t % 64;
        int jlo = max(0, q - 52), jhi = min(22, q + 11);
        float s = 0.f;
        for (int j = jlo; j <= jhi; ++j) s += e[i * 23 + j];
        colsum[i][q] = s;
    }
    __syncthreads();
    for (int tt = threadIdx.x; tt < 1024; tt += 256) {
        int t = quarter * 1024 + tt;
        int p = t >> 6, q = t & 63;
        int ilo = max(0, p - 52), ihi = min(22, p + 11);
        float s = 0.f;
        for (int i = ilo; i <= ihi; ++i) s += colsum[i][q];
        Wt[(size_t)hk * WH + t] = s;
    }
}

// ---- q/k 1x1 projections + BN + per-chunk softmax partials.
// 512 thr = 8 waves: waves 0..3 do q rows, 4..7 do k rows (4 rows each).
// Thread handles 4 px via float4. Weight reads are wave-uniform (scalar). ----
__global__ __launch_bounds__(512) void proj_kernel(
    const float* __restrict__ x,
    const float* __restrict__ qw, const float* __restrict__ kw,
    const float* __restrict__ qg, const float* __restrict__ qb,
    const float* __restrict__ qm, const float* __restrict__ qv,
    const float* __restrict__ kg, const float* __restrict__ kb,
    const float* __restrict__ km, const float* __restrict__ kv,
    float* __restrict__ qbn, float* __restrict__ kkbn, float* __restrict__ pstats)
{
    int t = threadIdx.x;
    int b = blockIdx.x >> 4, chunk = blockIdx.x & 15;
    int lane = t & 63;
    int og = __builtin_amdgcn_readfirstlane(t >> 6);   // 0..7, wave-uniform
    int isK = og >> 2;
    int o4 = (og & 3) * 4;
    int xy = chunk * 256 + lane * 4;

    const float* wsrc = isK ? kw : qw;
    const float* w0 = wsrc + (size_t)(o4 + 0) * 256;
    const float* w1 = wsrc + (size_t)(o4 + 1) * 256;
    const float* w2 = wsrc + (size_t)(o4 + 2) * 256;
    const float* w3 = wsrc + (size_t)(o4 + 3) * 256;

    float4 a0 = {0,0,0,0}, a1 = {0,0,0,0}, a2 = {0,0,0,0}, a3 = {0,0,0,0};
    const float* xb = x + (size_t)b * C_ * WH + xy;
#pragma unroll 8
    for (int c = 0; c < 256; ++c) {
        float4 xv = *(const float4*)(xb + (size_t)c * WH);
        float f0 = w0[c], f1 = w1[c], f2 = w2[c], f3 = w3[c];
        a0.x += xv.x*f0; a0.y += xv.y*f0; a0.z += xv.z*f0; a0.w += xv.w*f0;
        a1.x += xv.x*f1; a1.y += xv.y*f1; a1.z += xv.z*f1; a1.w += xv.w*f1;
        a2.x += xv.x*f2; a2.y += xv.y*f2; a2.z += xv.z*f2; a2.w += xv.w*f2;
        a3.x += xv.x*f3; a3.y += xv.y*f3; a3.z += xv.z*f3; a3.w += xv.w*f3;
    }
    float4 acc4[4] = {a0, a1, a2, a3};

    if (!isK) {
#pragma unroll
        for (int i = 0; i < 4; ++i) {
            int hk = o4 + i;
            float s  = qg[hk] * rsqrtf(qv[hk] + 1e-5f);
            float tq = qb[hk] - qm[hk] * s;
            float4 a = acc4[i], o;
            o.x = a.x * s + tq; o.y = a.y * s + tq;
            o.z = a.z * s + tq; o.w = a.w * s + tq;
            *(float4*)(qbn + ((size_t)b * 16 + hk) * WH + xy) = o;
        }
    } else {
#pragma unroll
        for (int i = 0; i < 4; ++i) {
            int hk = o4 + i;
            float s2 = kg[hk] * rsqrtf(kv[hk] + 1e-5f);
            float tk = kb[hk] - km[hk] * s2;
            float4 a = acc4[i], o;
            o.x = a.x * s2 + tk; o.y = a.y * s2 + tk;
            o.z = a.z * s2 + tk; o.w = a.w * s2 + tk;
            *(float4*)(kkbn + ((size_t)b * 16 + hk) * WH + xy) = o;
            // per-chunk softmax partials: wave = chunk (64 lanes x 4 px = 256 px)
            float m = fmaxf(fmaxf(o.x, o.y), fmaxf(o.z, o.w));
#pragma unroll
            for (int off = 32; off; off >>= 1) m = fmaxf(m, __shfl_xor(m, off, 64));
            float e = __expf(o.x - m) + __expf(o.y - m) + __expf(o.z - m) + __expf(o.w - m);
#pragma unroll
            for (int off = 32; off; off >>= 1) e += __shfl_xor(e, off, 64);
            if (lane == 0) {
                float* ps = pstats + ((size_t)(b * 16 + hk) * 16 + chunk) * 2;
                ps[0] = m; ps[1] = e;
            }
        }
    }
}

// ---- U/T contractions, LDS-traffic-minimized.
// Grid 256 = (b, seg of 256 xy). 512 thr = 8 waves.
// wave -> (rgrp = wid&3, chalf = wid>>2); thread: c in {cb, cb+128}, 8 rows
// (4 U rows rgrp*4+rr and 4 T rows 16+rgrp*4+rr). All w reads are
// wave-uniform LDS broadcasts; x reads are 2 b128 per 4-xy step.
// x tiles (32 xy) double-buffered with reg-staged prefetch. ----
__global__ __launch_bounds__(512) void ut_kernel(
    const float* __restrict__ x, const float* __restrict__ kkbn,
    const float* __restrict__ stats, const float* __restrict__ Wt,
    float* __restrict__ Mpart)
{
    __shared__ __align__(16) float wls[32][260];     // w rows, whole seg (33.3 KB)
    __shared__ __align__(16) float xls[2][256][36];  // x subtiles, dbuf (73.7 KB)
    int t = threadIdx.x;
    int b = blockIdx.x >> 4, seg = blockIdx.x & 15;
    int xys0 = seg * 256;
    int lane = t & 63, wid = t >> 6;
    int rgrp = wid & 3, chalf = wid >> 2;
    int cb = chalf * 64 + lane;                      // 0..127

    // ---- stage w rows (sm for r<16, Wt for r>=16) for the whole seg ----
    {
        int r = t >> 4;              // 0..31
        int xo = (t & 15) * 16;      // 16 xy per thread
        if (r < 16) {
            float mm  = stats[(b * 16 + r) * 2 + 0];
            float inv = stats[(b * 16 + r) * 2 + 1];
            const float* src = kkbn + ((size_t)b * 16 + r) * WH + xys0 + xo;
#pragma unroll
            for (int j = 0; j < 16; j += 4) {
                float4 v = *(const float4*)(src + j);
                wls[r][xo + j + 0] = __expf(v.x - mm) * inv;
                wls[r][xo + j + 1] = __expf(v.y - mm) * inv;
                wls[r][xo + j + 2] = __expf(v.z - mm) * inv;
                wls[r][xo + j + 3] = __expf(v.w - mm) * inv;
            }
        } else {
            const float* src = Wt + (size_t)(r - 16) * WH + xys0 + xo;
#pragma unroll
            for (int j = 0; j < 16; j += 4)
                *(float4*)&wls[r][xo + j] = *(const float4*)(src + j);
        }
    }

    const float* xbase = x + (size_t)b * C_ * WH + xys0;
    float4 st4[4];
    // prologue: load + write sub 0
#pragma unroll
    for (int i = 0; i < 4; ++i) {
        int id = t + i * 512, c = id >> 3, k = id & 7;
        st4[i] = *(const float4*)(xbase + (size_t)c * WH + k * 4);
    }
#pragma unroll
    for (int i = 0; i < 4; ++i) {
        int id = t + i * 512, c = id >> 3, k = id & 7;
        *(float4*)&xls[0][c][k * 4] = st4[i];
    }

    float acc[8][2] = {};
    int cur = 0;
    for (int sub = 0; sub < 8; ++sub) {
        if (sub < 7) {               // issue next tile's global loads (overlap compute)
#pragma unroll
            for (int i = 0; i < 4; ++i) {
                int id = t + i * 512, c = id >> 3, k = id & 7;
                st4[i] = *(const float4*)(xbase + (size_t)c * WH + (sub + 1) * 32 + k * 4);
            }
        }
        __syncthreads();             // xls[cur] writes visible; prev readers done
        int xw = sub * 32;
#pragma unroll
        for (int q = 0; q < 8; ++q) {
            float4 xa = *(const float4*)&xls[cur][cb][q * 4];
            float4 xc = *(const float4*)&xls[cur][cb + 128][q * 4];
#pragma unroll
            for (int rr = 0; rr < 8; ++rr) {
                int row = (rr < 4) ? (rgrp * 4 + rr) : (12 + rgrp * 4 + rr);
                float4 w4 = *(const float4*)&wls[row][xw + q * 4];  // broadcast
                acc[rr][0] += xa.x*w4.x + xa.y*w4.y + xa.z*w4.z + xa.w*w4.w;
                acc[rr][1] += xc.x*w4.x + xc.y*w4.y + xc.z*w4.z + xc.w*w4.w;
            }
        }
        if (sub < 7) {               // write prefetched tile into the other buffer
#pragma unroll
            for (int i = 0; i < 4; ++i) {
                int id = t + i * 512, c = id >> 3, k = id & 7;
                *(float4*)&xls[cur ^ 1][c][k * 4] = st4[i];
            }
            cur ^= 1;
        }
    }

    float* mp = Mpart + ((size_t)b * 16 + seg) * 32 * 256;
#pragma unroll
    for (int rr = 0; rr < 8; ++rr) {
        int row = (rr < 4) ? (rgrp * 4 + rr) : (12 + rgrp * 4 + rr);
        mp[row * 256 + cb]       = acc[rr][0];
        mp[row * 256 + cb + 128] = acc[rr][1];
    }
}

// ---- lambda[b,hk,v] = sum_c v_w[h,v,c] * (U+T)[b,hk,c]. One block per (b,hk). ----
__global__ __launch_bounds__(256) void lam_kernel(
    const float* __restrict__ Mpart, const float* __restrict__ vw,
    float* __restrict__ lam)
{
    __shared__ float msum[256];
    __shared__ float vls[64][68];
    __shared__ float psum[4][64];
    int t = threadIdx.x;
    int b = blockIdx.x >> 4, hk = blockIdx.x & 15, h = hk >> 2;

    {
        const float* mp = Mpart + (size_t)b * 16 * 8192 + t;
        float s = 0.f;
        for (int seg = 0; seg < 16; ++seg) {
            const float* m2 = mp + (size_t)seg * 8192;
            s += m2[hk * 256] + m2[(16 + hk) * 256];
        }
        msum[t] = s;
    }

    int v = t & 63, cq = t >> 6;
    float acc = 0.f;
    const float* vwh = vw + (size_t)h * 64 * 256;
    for (int ch = 0; ch < 4; ++ch) {
        __syncthreads();
#pragma unroll
        for (int k = 0; k < 4; ++k) {
            int e = t + k * 256;
            int vv = e >> 4, c4 = (e & 15) * 4;
            *(float4*)&vls[vv][c4] = *(const float4*)(vwh + (size_t)vv * 256 + ch * 64 + c4);
        }
        __syncthreads();
#pragma unroll
        for (int i4 = 0; i4 < 4; ++i4) {
            float4 a  = *(const float4*)&vls[v][cq * 16 + i4 * 4];
            float4 m4 = *(const float4*)&msum[ch * 64 + cq * 16 + i4 * 4];
            acc += a.x * m4.x + a.y * m4.y + a.z * m4.z + a.w * m4.w;
        }
    }
    psum[cq][v] = acc;
    __syncthreads();
    if (t < 64)
        lam[((size_t)b * 16 + hk) * 64 + t] =
            psum[0][t] + psum[1][t] + psum[2][t] + psum[3][t];
}

// ---- out[b, h*64+v, xy] = sum_k qbn[b,hk,xy] * lam[b,hk,v].
// Block = (b, h, xy-quarter); thread = xy-quad (float4 loads/stores);
// lam reads wave-uniform (scalar). ----
__global__ __launch_bounds__(256) void out_kernel(
    const float* __restrict__ qbn, const float* __restrict__ lam,
    float* __restrict__ out)
{
    int t = threadIdx.x;
    int b = blockIdx.x >> 4, s = blockIdx.x & 15;
    int h = s >> 2, qc = s & 3;
    int xy = qc * 1024 + t * 4;
    float4 q0 = *(const float4*)(qbn + ((size_t)b * 16 + h * 4 + 0) * WH + xy);
    float4 q1 = *(const float4*)(qbn + ((size_t)b * 16 + h * 4 + 1) * WH + xy);
    float4 q2 = *(const float4*)(qbn + ((size_t)b * 16 + h * 4 + 2) * WH + xy);
    float4 q3 = *(const float4*)(qbn + ((size_t)b * 16 + h * 4 + 3) * WH + xy);
    const float* lb = lam + (size_t)b * 1024 + (size_t)h * 256;
    float* ob = out + ((size_t)b * 256 + (size_t)h * 64) * WH + xy;
#pragma unroll 8
    for (int v = 0; v < 64; ++v) {
        float l0 = lb[v], l1 = lb[64 + v], l2 = lb[128 + v], l3 = lb[192 + v];
        float4 o;
        o.x = q0.x*l0 + q1.x*l1 + q2.x*l2 + q3.x*l3;
        o.y = q0.y*l0 + q1.y*l1 + q2.y*l2 + q3.y*l3;
        o.z = q0.z*l0 + q1.z*l1 + q2.z*l2 + q3.z*l3;
        o.w = q0.w*l0 + q1.w*l1 + q2.w*l2 + q3.w*l3;
        *(float4*)(ob + (size_t)v * WH) = o;
    }
}

extern "C" void kernel_launch(void* const* d_in, const int* in_sizes, int n_in,
                              void* d_out, int out_size, void* d_ws, size_t ws_size,
                              hipStream_t stream)
{
    const float* x   = (const float*)d_in[0];
    const float* qw  = (const float*)d_in[1];
    const float* qg  = (const float*)d_in[2];
    const float* qb  = (const float*)d_in[3];
    const float* qm  = (const float*)d_in[4];
    const float* qv  = (const float*)d_in[5];
    const float* kw  = (const float*)d_in[6];
    const float* kg  = (const float*)d_in[7];
    const float* kb  = (const float*)d_in[8];
    const float* km  = (const float*)d_in[9];
    const float* kv  = (const float*)d_in[10];
    const float* vw  = (const float*)d_in[11];
    const float* emb = (const float*)d_in[12];

    float* ws    = (float*)d_ws;
    float* qbn   = ws;
    float* kkbn  = ws + 1048576;
    float* stats = ws + 2097152;
    float* Wt    = ws + 2097664;
    float* Mpart = ws + 2163200;
    float* pstats = Mpart;            // alias: proj writes, wtcomb reads, ut overwrites
    float* lam   = ws + 4260352;
    float* out   = (float*)d_out;

    hipLaunchKernelGGL(proj_kernel,  dim3(256), dim3(512), 0, stream,
                       x, qw, kw, qg, qb, qm, qv, kg, kb, km, kv, qbn, kkbn, pstats);
    hipLaunchKernelGGL(wtcomb_kernel, dim3(65), dim3(256), 0, stream, emb, pstats, Wt, stats);
    hipLaunchKernelGGL(ut_kernel,    dim3(256), dim3(512), 0, stream,
                       x, kkbn, stats, Wt, Mpart);
    hipLaunchKernelGGL(lam_kernel,   dim3(256), dim3(256), 0, stream, Mpart, vw, lam);
    hipLaunchKernelGGL(out_kernel,   dim3(256), dim3(256), 0, stream, qbn, lam, out);
}